// Round 11
// baseline (44027.762 us; speedup 1.0000x reference)
//
#include <hip/hip_runtime.h>

#define NBLK 256
#define NTHR 512

typedef float f32x4 __attribute__((ext_vector_type(4)));
typedef unsigned int u32;

// ---------------- math helpers ----------------
__device__ __forceinline__ float sigm(float x){ return 1.f/(1.f+__expf(-x)); }
__device__ __forceinline__ float tanh_(float x){ return 1.f - 2.f/(__expf(2.f*x)+1.f); }

__device__ __forceinline__ float wred_sum(float v){
  #pragma unroll
  for (int off=32; off; off>>=1) v += __shfl_xor(v, off, 64);
  return v;
}

// bf16 pack/unpack
__device__ __forceinline__ u32 cvtpk(float lo, float hi){
  u32 r; asm("v_cvt_pk_bf16_f32 %0,%1,%2":"=v"(r):"v"(lo),"v"(hi)); return r;
}
__device__ __forceinline__ float bflo(u32 u){ return __uint_as_float(u<<16); }
__device__ __forceinline__ float bfhi(u32 u){ return __uint_as_float(u & 0xFFFF0000u); }

// agent-coherent (sc1) store/load
__device__ __forceinline__ void st_sys(float* p, float v){
  __hip_atomic_store(p, v, __ATOMIC_RELAXED, __HIP_MEMORY_SCOPE_AGENT);
}
__device__ __forceinline__ void st_sysu(u32* p, u32 v){
  __hip_atomic_store(p, v, __ATOMIC_RELAXED, __HIP_MEMORY_SCOPE_AGENT);
}
__device__ __forceinline__ float ald(const float* p){
  return __hip_atomic_load(p, __ATOMIC_RELAXED, __HIP_MEMORY_SCOPE_AGENT);
}
__device__ __forceinline__ u32 aldu(const u32* p){
  return __hip_atomic_load(p, __ATOMIC_RELAXED, __HIP_MEMORY_SCOPE_AGENT);
}

// counted vmcnt wait (literal immediate) + scheduling pin (rule 18)
template<int N> __device__ __forceinline__ void vmwait(){
  #define VMC(n) if constexpr (N==n) asm volatile("s_waitcnt vmcnt(" #n ")":::"memory");
  VMC(0) VMC(1) VMC(2) VMC(3) VMC(4) VMC(5) VMC(6) VMC(7) VMC(8) VMC(9) VMC(10)
  VMC(11) VMC(12) VMC(13) VMC(14) VMC(15) VMC(16) VMC(17) VMC(18) VMC(19) VMC(20) VMC(21)
  #undef VMC
  __builtin_amdgcn_sched_barrier(0);
}
// LDS-writes-visible barrier without draining vmcnt (keeps prefetches alive)
__device__ __forceinline__ void lgkm0_bar(){
  asm volatile("s_waitcnt lgkmcnt(0)":::"memory");
  __builtin_amdgcn_sched_barrier(0);
  __builtin_amdgcn_s_barrier();
  __builtin_amdgcn_sched_barrier(0);
}

// tree-arrive + single-root-release grid barrier, epoch-based (r5 structure)
__device__ __forceinline__ void gsync(unsigned* bar, int w, unsigned& ep){
  ++ep;
  __builtin_amdgcn_s_waitcnt(0);          // drain this wave's sc1 stores + prefetches
  __syncthreads();
  if (threadIdx.x == 0){
    const unsigned epoch = ep;
    const int g = w >> 4;
    unsigned o = __hip_atomic_fetch_add(bar + g*32, 1u, __ATOMIC_ACQ_REL, __HIP_MEMORY_SCOPE_AGENT);
    if (o == 15u){
      __hip_atomic_store(bar + g*32, 0u, __ATOMIC_RELAXED, __HIP_MEMORY_SCOPE_AGENT);
      unsigned o2 = __hip_atomic_fetch_add(bar + 16*32, 1u, __ATOMIC_ACQ_REL, __HIP_MEMORY_SCOPE_AGENT);
      if (o2 == 15u){
        __hip_atomic_store(bar + 16*32, 0u, __ATOMIC_RELAXED, __HIP_MEMORY_SCOPE_AGENT);
        __hip_atomic_store(bar + 17*32, epoch, __ATOMIC_RELEASE, __HIP_MEMORY_SCOPE_AGENT);
      } else {
        while (__hip_atomic_load(bar+17*32, __ATOMIC_RELAXED, __HIP_MEMORY_SCOPE_AGENT) < epoch)
          __builtin_amdgcn_s_sleep(1);
      }
    } else {
      while (__hip_atomic_load(bar+17*32, __ATOMIC_RELAXED, __HIP_MEMORY_SCOPE_AGENT) < epoch)
        __builtin_amdgcn_s_sleep(1);
    }
  }
  __syncthreads();
}

// ---------------- LSTM layer: full-depth prefetch + counted vmcnt ----------
// WG w owns 8 gate-rows (2 j x 4 gates); wave r = row (gate=r&3, j=2w+(r>>2)).
// thread holds W[row][i*256 + lane*4 + j] in registers (mapping unchanged).
// Chunk = 8 batch rows; wave r stages batch-row r of the chunk: lane l loads
// 8 consecutive u32 (16 bf16) at inu[(ch*8+r)*512 + l*8] -> LDS.
// Gate dot = per-wave over all k: wred_sum. Cell update by tid<16.

template<int CH, bool L0T>
__device__ __forceinline__ void chunk_issue(const u32* __restrict__ inu, int r, int lane,
                                            const float* __restrict__ tgt, int t,
                                            uint4& a, uint4& b, f32x4& x){
  const u32* p = inu + CH*4096 + r*512 + lane*8;
  asm volatile("global_load_dwordx4 %0, %1, off sc0 sc1" : "=v"(a) : "v"(p));
  asm volatile("global_load_dwordx4 %0, %1, off sc0 sc1" : "=v"(b) : "v"(p+4));
  if constexpr (L0T){
    const int gb = CH*8 + r;
    const int xo = (lane < 20) ? (lane<<2) : 0;
    const float* q = tgt + ((gb<<8)+t)*80 + xo;
    asm volatile("global_load_dwordx4 %0, %1, off" : "=v"(x) : "v"(q));
  }
}

template<int NI, bool L0T, int W, int CH>
__device__ __forceinline__ void chunk_exec(
    u32* Su, float* xs, int r, int lane, int tid,
    const uint4& a, const uint4& b, const f32x4& xv,
    const float (&wt)[NI][4], float br,
    float* sG4, float* sc_c,
    u32* __restrict__ dstA, int strAu,
    u32* __restrict__ dstB, int strBu)
{
  vmwait<W>();                                  // chunk CH's loads resident
  *(uint4*)(Su + r*512 + lane*8)     = a;
  *(uint4*)(Su + r*512 + lane*8 + 4) = b;
  if constexpr (L0T){ if (lane < 20) *(f32x4*)(xs + r*80 + (lane<<2)) = xv; }
  lgkm0_bar();                                  // stage visible (no vmcnt drain)

  float p[8];
  #pragma unroll
  for (int bb=0; bb<8; ++bb){
    const u32* row = Su + bb*512 + (lane<<1);
    float a0=0.f,a1=0.f,a2=0.f,a3=0.f;
    #pragma unroll
    for (int i=0;i<4;++i){
      const uint2 e = *(const uint2*)(row + (i<<7));
      a0 = fmaf(wt[i][0], bflo(e.x), a0);
      a1 = fmaf(wt[i][1], bfhi(e.x), a1);
      a2 = fmaf(wt[i][2], bflo(e.y), a2);
      a3 = fmaf(wt[i][3], bfhi(e.y), a3);
    }
    if constexpr (L0T){
      if (lane < 20){
        const float4 xq = *(const float4*)(xs + bb*80 + (lane<<2));
        a0 = fmaf(wt[4][0], xq.x, a0);
        a1 = fmaf(wt[4][1], xq.y, a1);
        a2 = fmaf(wt[4][2], xq.z, a2);
        a3 = fmaf(wt[4][3], xq.w, a3);
      }
    }
    p[bb] = (a0+a1)+(a2+a3);
  }
  #pragma unroll
  for (int bb=0; bb<8; ++bb){
    const float v = wred_sum(p[bb]);            // full-k dot for (row r, batch bb)
    if (lane==0) sG4[(bb<<3)|r] = v + br;
  }
  lgkm0_bar();                                  // sG4 visible; stage reads done

  if (tid < 16){
    const int bb = tid>>1, jl = tid&1;
    const float gi = sigm (sG4[(bb<<3) + (jl<<2) + 0]);
    const float gf = sigm (sG4[(bb<<3) + (jl<<2) + 1]);
    const float gg = tanh_(sG4[(bb<<3) + (jl<<2) + 2]);
    const float go = sigm (sG4[(bb<<3) + (jl<<2) + 3]);
    const float cn = gf*sc_c[(CH<<4)+tid] + gi*gg;
    sc_c[(CH<<4)+tid] = cn;
    const float hn = go * tanh_(cn);
    const float hn1 = __shfl(hn, tid^1, 64);
    if (!(tid&1)){
      const u32 hp = cvtpk(hn, hn1);            // (j=2w, j=2w+1)
      st_sysu(dstA + (CH*8+bb)*strAu, hp);
      st_sysu(dstB + (CH*8+bb)*strBu, hp);
    }
  }
  // next chunk's first lgkm0_bar orders cell update vs. stage/sG4 reuse
}

template<int NI, bool L0T>
__device__ __forceinline__ void lstm_layer(
    int w, int tid, const float (&wt)[NI][4], float br,
    const u32* __restrict__ inu, float* sc_c,
    u32* __restrict__ dstA, int strAu,
    u32* __restrict__ dstB, int strBu,
    u32* Su, float* xs, float* sG4,
    const float* __restrict__ tgt, int t)
{
  const int lane = tid & 63, r = tid >> 6;
  uint4 a[8], b[8]; f32x4 x[8];
  chunk_issue<0,L0T>(inu,r,lane,tgt,t,a[0],b[0],x[0]);
  chunk_issue<1,L0T>(inu,r,lane,tgt,t,a[1],b[1],x[1]);
  chunk_issue<2,L0T>(inu,r,lane,tgt,t,a[2],b[2],x[2]);
  chunk_issue<3,L0T>(inu,r,lane,tgt,t,a[3],b[3],x[3]);
  chunk_issue<4,L0T>(inu,r,lane,tgt,t,a[4],b[4],x[4]);
  chunk_issue<5,L0T>(inu,r,lane,tgt,t,a[5],b[5],x[5]);
  chunk_issue<6,L0T>(inu,r,lane,tgt,t,a[6],b[6],x[6]);
  chunk_issue<7,L0T>(inu,r,lane,tgt,t,a[7],b[7],x[7]);
  constexpr int PC = L0T ? 3 : 2;
  chunk_exec<NI,L0T,PC*7,0>(Su,xs,r,lane,tid,a[0],b[0],x[0],wt,br,sG4,sc_c,dstA,strAu,dstB,strBu);
  chunk_exec<NI,L0T,PC*6,1>(Su,xs,r,lane,tid,a[1],b[1],x[1],wt,br,sG4,sc_c,dstA,strAu,dstB,strBu);
  chunk_exec<NI,L0T,PC*5,2>(Su,xs,r,lane,tid,a[2],b[2],x[2],wt,br,sG4,sc_c,dstA,strAu,dstB,strBu);
  chunk_exec<NI,L0T,PC*4,3>(Su,xs,r,lane,tid,a[3],b[3],x[3],wt,br,sG4,sc_c,dstA,strAu,dstB,strBu);
  chunk_exec<NI,L0T,PC*3,4>(Su,xs,r,lane,tid,a[4],b[4],x[4],wt,br,sG4,sc_c,dstA,strAu,dstB,strBu);
  chunk_exec<NI,L0T,PC*2,5>(Su,xs,r,lane,tid,a[5],b[5],x[5],wt,br,sG4,sc_c,dstA,strAu,dstB,strBu);
  chunk_exec<NI,L0T,PC*1,6>(Su,xs,r,lane,tid,a[6],b[6],x[6],wt,br,sG4,sc_c,dstA,strAu,dstB,strBu);
  chunk_exec<NI,L0T,   0,7>(Su,xs,r,lane,tid,a[7],b[7],x[7],wt,br,sG4,sc_c,dstA,strAu,dstB,strBu);
}

// ---- ws layout (after 8KB barrier area), in UINTS ----
#define ZERO_U   212992
#define FP_OFF   212992
#define ENC_OFF  475648
#define ENC_CNT  8388608

__global__ __launch_bounds__(NTHR, 2)
void sd_kernel(const float* __restrict__ tgt,  const float* __restrict__ enc,
               const int*   __restrict__ lens,
               const float* __restrict__ Wih0, const float* __restrict__ Whh0, const float* __restrict__ b0v,
               const float* __restrict__ Wih1, const float* __restrict__ Whh1, const float* __restrict__ b1v,
               const float* __restrict__ Wih2, const float* __restrict__ Whh2, const float* __restrict__ b2v,
               const float* __restrict__ Wq,   const float* __restrict__ Wfc,  const float* __restrict__ bfc,
               float* __restrict__ out, void* __restrict__ wsv, int ebf)
{
  unsigned* bar = (unsigned*)wsv;
  u32* wsu = (u32*)((char*)wsv + 8192);
  u32* IN0u = wsu;
  u32* IN1u = wsu + 65536;
  u32* IN2u = wsu + 131072;
  u32* H2u  = wsu + 196608;
  float* F  = (float*)(wsu + FP_OFF);
  float* QP = F;
  float* PC = F + 131072;
  float* MS = F + 262144;
  u32* encbfu = wsu + ENC_OFF;

  const int w = blockIdx.x, tid = threadIdx.x;
  const int lane = tid & 63, r = tid >> 6;
  unsigned ep = 0;

  __shared__ __attribute__((aligned(16))) u32   Su[4096];     // bf16 chunk stage (16KB)
  __shared__ __attribute__((aligned(16))) float xs[640];      // L0 x stage (8 rows x 80)
  __shared__ __attribute__((aligned(16))) float sG4[64];
  __shared__ __attribute__((aligned(16))) float sBig[4096];   // attn wave-ctx
  __shared__ __attribute__((aligned(16))) float sVec[512];
  __shared__ __attribute__((aligned(16))) float sSmall[16];
  __shared__ __attribute__((aligned(16))) float sc_c[384];    // 128 cells per layer

  // ---- prologue: weights -> registers (normal cached; mapping unchanged) ----
  const int wrow = ((r&3)<<9) + (w<<1) + (r>>2);

  float w0r[5][4], w1r[4][4], w2r[4][4];
  #pragma unroll
  for (int i=0;i<5;++i){
    #pragma unroll
    for (int j=0;j<4;++j){
      const int k = (i<<8) + (lane<<2) + j;
      float v;
      if (k < 512)       v = Wih0[wrow*592 + 80 + k];        // ctx block
      else if (k < 1024) v = Whh0[(wrow<<9) + (k-512)];      // h0 block
      else if (k < 1104) v = Wih0[wrow*592 + (k-1024)];      // x block
      else               v = 0.f;                            // pad
      w0r[i][j] = v;
    }
  }
  #pragma unroll
  for (int i=0;i<4;++i){
    #pragma unroll
    for (int j=0;j<4;++j){
      const int k = (i<<8) + (lane<<2) + j;
      w1r[i][j] = (k<512) ? Wih1[(wrow<<9)+k] : Whh1[(wrow<<9)+k-512];
      w2r[i][j] = (k<512) ? Wih2[(wrow<<9)+k] : Whh2[(wrow<<9)+k-512];
    }
  }
  const float br0 = b0v[wrow], br1 = b1v[wrow], br2 = b2v[wrow];  // wave-uniform

  if (tid < 384) sc_c[tid] = 0.f;
  for (int i = w*NTHR + tid; i < ZERO_U; i += NBLK*NTHR) st_sysu(wsu + i, 0u);
  if (ebf){
    for (int i = w*NTHR + tid; i < ENC_CNT; i += NBLK*NTHR)
      st_sysu(encbfu + i, cvtpk(enc[2*i], enc[2*i+1]));
  }
  gsync(bar, w, ep);

  for (int t=0; t<255; ++t){
    const int p = t & 1, np = p ^ 1;
    u32* IN0p = IN0u + p*32768;  u32* IN0n = IN0u + np*32768;
    u32* IN1p = IN1u + p*32768;  u32* IN1n = IN1u + np*32768;
    u32* IN2p = IN2u + p*32768;  u32* IN2n = IN2u + np*32768;

    lstm_layer<5,true >(w,tid, w0r, br0, IN0p, sc_c,
                        IN0n+256+w, 512, IN1p+w, 512, Su, xs, sG4, tgt, t);
    gsync(bar,w,ep);
    lstm_layer<4,false>(w,tid, w1r, br1, IN1p, sc_c+128,
                        IN1n+256+w, 512, IN2p+w, 512, Su, xs, sG4, tgt, t);
    gsync(bar,w,ep);
    lstm_layer<4,false>(w,tid, w2r, br2, IN2p, sc_c+256,
                        IN2n+256+w, 512, H2u+w, 256, Su, xs, sG4, tgt, t);
    gsync(bar,w,ep);

    // ---- q partials: WG (b = w&63, kq = w>>6) over k-quarter ----
    {
      const int b = w & 63, kq = w >> 6;
      if (tid < 64){
        const u32 u = aldu(H2u + b*256 + kq*64 + tid);
        sVec[2*tid]   = bflo(u);
        sVec[2*tid+1] = bfhi(u);
      }
      __syncthreads();
      const float* wqp = Wq + ((size_t)(kq<<7)<<9) + tid;
      float acc = 0.f;
      #pragma unroll 4
      for (int k=0;k<128;++k) acc = fmaf(sVec[k], wqp[(size_t)k<<9], acc);
      st_sys(&QP[(((kq<<6)+b)<<9) + tid], acc);
    }
    gsync(bar,w,ep);

    // ---- attention A: WG (b, sq): online-softmax over 128 enc rows ----
    {
      const int b = w & 63, sq = w >> 6;
      const int len  = lens[b];
      const int wv = tid >> 6;
      sVec[tid] = ald(&QP[(b<<9)+tid]) + ald(&QP[((64+b)<<9)+tid])
                + ald(&QP[((128+b)<<9)+tid]) + ald(&QP[((192+b)<<9)+tid]);
      __syncthreads();
      const float4 qA = *(const float4*)(sVec + (lane<<3));
      const float4 qB = *(const float4*)(sVec + (lane<<3) + 4);
      float mr = -3.0e38f, lr = 0.f;
      float c0=0,c1=0,c2=0,c3=0,c4=0,c5=0,c6=0,c7=0;
      const float scale = 0.04419417382415922f;
      if (ebf){
        const u32* ebase = encbfu + (((size_t)b)<<17) + (lane<<2);
        #pragma unroll 1
        for (int rr=0; rr<16; ++rr){
          const int srow = (sq<<7) + (wv<<4) + rr;
          if (srow >= len) break;
          const uint4 eu = *(const uint4*)(ebase + ((size_t)srow<<8));
          const float e0=bflo(eu.x), e1=bfhi(eu.x), e2=bflo(eu.y), e3=bfhi(eu.y);
          const float e4=bflo(eu.z), e5=bfhi(eu.z), e6=bflo(eu.w), e7=bfhi(eu.w);
          float d0 = qA.x*e0, d1 = qA.y*e1, d2 = qA.z*e2, d3 = qA.w*e3;
          d0 = fmaf(qB.x, e4, d0); d1 = fmaf(qB.y, e5, d1);
          d2 = fmaf(qB.z, e6, d2); d3 = fmaf(qB.w, e7, d3);
          float d = wred_sum((d0+d1)+(d2+d3));
          const float sc = d*scale;
          const float mn = fmaxf(mr, sc);
          const float sf = __expf(mr - mn);
          const float pe = __expf(sc - mn);
          lr = fmaf(lr, sf, pe);
          c0 = fmaf(c0, sf, pe*e0); c1 = fmaf(c1, sf, pe*e1);
          c2 = fmaf(c2, sf, pe*e2); c3 = fmaf(c3, sf, pe*e3);
          c4 = fmaf(c4, sf, pe*e4); c5 = fmaf(c5, sf, pe*e5);
          c6 = fmaf(c6, sf, pe*e6); c7 = fmaf(c7, sf, pe*e7);
          mr = mn;
        }
      } else {
        #pragma unroll 1
        for (int rr=0; rr<16; ++rr){
          const int srow = (sq<<7) + (wv<<4) + rr;
          if (srow >= len) break;
          const float* ep2 = enc + (((size_t)(b<<9)+srow)<<9) + (lane<<3);
          const float4 e0v = *(const float4*)(ep2);
          const float4 e1v = *(const float4*)(ep2+4);
          float d0 = qA.x*e0v.x, d1 = qA.y*e0v.y, d2 = qA.z*e0v.z, d3 = qA.w*e0v.w;
          d0 = fmaf(qB.x, e1v.x, d0); d1 = fmaf(qB.y, e1v.y, d1);
          d2 = fmaf(qB.z, e1v.z, d2); d3 = fmaf(qB.w, e1v.w, d3);
          float d = wred_sum((d0+d1)+(d2+d3));
          const float sc = d*scale;
          const float mn = fmaxf(mr, sc);
          const float sf = __expf(mr - mn);
          const float pe = __expf(sc - mn);
          lr = fmaf(lr, sf, pe);
          c0 = fmaf(c0, sf, pe*e0v.x); c1 = fmaf(c1, sf, pe*e0v.y);
          c2 = fmaf(c2, sf, pe*e0v.z); c3 = fmaf(c3, sf, pe*e0v.w);
          c4 = fmaf(c4, sf, pe*e1v.x); c5 = fmaf(c5, sf, pe*e1v.y);
          c6 = fmaf(c6, sf, pe*e1v.z); c7 = fmaf(c7, sf, pe*e1v.w);
          mr = mn;
        }
      }
      if (lane==0){ sSmall[wv] = mr; sSmall[8+wv] = lr; }
      {
        float4 v0 = {c0,c1,c2,c3}, v1 = {c4,c5,c6,c7};
        *(float4*)(sBig + (wv<<9) + (lane<<3))     = v0;
        *(float4*)(sBig + (wv<<9) + (lane<<3) + 4) = v1;
      }
      __syncthreads();
      float M = sSmall[0];
      #pragma unroll
      for (int i=1;i<8;++i) M = fmaxf(M, sSmall[i]);
      float L = 0.f, acc = 0.f;
      #pragma unroll
      for (int i=0;i<8;++i){
        const float A = __expf(sSmall[i]-M);
        L   = fmaf(A, sSmall[8+i], L);
        acc = fmaf(A, sBig[(i<<9)+tid], acc);
      }
      st_sys(&PC[(((sq<<6)+b)<<9)+tid], acc);
      if (tid==0){
        st_sys(&MS[(((sq<<6)+b)<<1)],   M);
        st_sys(&MS[(((sq<<6)+b)<<1)+1], L);
      }
    }
    gsync(bar,w,ep);

    // ---- attention B: combine + FC + out (WGs 0..63 only) ----
    if (w < 64){
      const int b = w;
      const float m0 = ald(&MS[(b)<<1]),      S0 = ald(&MS[((b)<<1)+1]);
      const float m1 = ald(&MS[(64+b)<<1]),   S1 = ald(&MS[((64+b)<<1)+1]);
      const float m2 = ald(&MS[(128+b)<<1]),  S2 = ald(&MS[((128+b)<<1)+1]);
      const float m3 = ald(&MS[(192+b)<<1]),  S3 = ald(&MS[((192+b)<<1)+1]);
      const float M  = fmaxf(fmaxf(m0,m1), fmaxf(m2,m3));
      const float a0=__expf(m0-M), a1=__expf(m1-M), a2=__expf(m2-M), a3=__expf(m3-M);
      const float inv = 1.f/(a0*S0 + a1*S1 + a2*S2 + a3*S3);
      const float c = (a0*ald(&PC[(b<<9)+tid])       + a1*ald(&PC[((64+b)<<9)+tid])
                     + a2*ald(&PC[((128+b)<<9)+tid]) + a3*ald(&PC[((192+b)<<9)+tid])) * inv;
      const float c1 = __shfl(c, tid^1, 64);
      if (!(tid&1)) st_sysu(IN0n + b*512 + (tid>>1), cvtpk(c, c1));
      sVec[tid] = c;
      __syncthreads();
      if (tid < 80){
        float acc = 0.f;
        #pragma unroll 4
        for (int e2=0;e2<512;++e2) acc = fmaf(sVec[e2], Wfc[e2*80+tid], acc);
        out[((size_t)b*255 + t)*80 + tid] = acc + bfc[tid];
      }
    }
    gsync(bar,w,ep);
  }
}

extern "C" void kernel_launch(void* const* d_in, const int* in_sizes, int n_in,
                              void* d_out, int out_size, void* d_ws, size_t ws_size,
                              hipStream_t stream) {
  const float* tgt  = (const float*)d_in[0];
  const float* enc  = (const float*)d_in[1];
  const int*   lens = (const int*)  d_in[2];
  const float* Wih0 = (const float*)d_in[3];
  const float* Whh0 = (const float*)d_in[4];
  const float* b0   = (const float*)d_in[5];
  const float* Wih1 = (const float*)d_in[6];
  const float* Whh1 = (const float*)d_in[7];
  const float* b1   = (const float*)d_in[8];
  const float* Wih2 = (const float*)d_in[9];
  const float* Whh2 = (const float*)d_in[10];
  const float* b2   = (const float*)d_in[11];
  const float* Wq   = (const float*)d_in[12];
  const float* Wfc  = (const float*)d_in[13];
  const float* bfc  = (const float*)d_in[14];

  const size_t need = 8192ull + ((size_t)ENC_OFF + (size_t)ENC_CNT)*4ull;
  const int ebf = (ws_size >= need) ? 1 : 0;

  hipMemsetAsync(d_ws, 0, 8192, stream);   // barrier counters
  sd_kernel<<<NBLK, NTHR, 0, stream>>>(tgt, enc, lens,
                                       Wih0, Whh0, b0,
                                       Wih1, Whh1, b1,
                                       Wih2, Whh2, b2,
                                       Wq, Wfc, bfc,
                                       (float*)d_out, d_ws, ebf);
}

// Round 12
// 33351.224 us; speedup vs baseline: 1.3201x; 1.3201x over previous
//
#include <hip/hip_runtime.h>

#define NBLK 256
#define NTHR 512

typedef float f32x4 __attribute__((ext_vector_type(4)));
typedef unsigned int u32;

// ---------------- math helpers ----------------
__device__ __forceinline__ float sigm(float x){ return 1.f/(1.f+__expf(-x)); }
__device__ __forceinline__ float tanh_(float x){ return 1.f - 2.f/(__expf(2.f*x)+1.f); }

__device__ __forceinline__ float wred_sum(float v){
  #pragma unroll
  for (int off=32; off; off>>=1) v += __shfl_xor(v, off, 64);
  return v;
}

// bf16 pack/unpack
__device__ __forceinline__ u32 cvtpk(float lo, float hi){
  u32 r; asm("v_cvt_pk_bf16_f32 %0,%1,%2":"=v"(r):"v"(lo),"v"(hi)); return r;
}
__device__ __forceinline__ float bflo(u32 u){ return __uint_as_float(u<<16); }
__device__ __forceinline__ float bfhi(u32 u){ return __uint_as_float(u & 0xFFFF0000u); }

// agent-coherent (sc1) store/load
__device__ __forceinline__ void st_sys(float* p, float v){
  __hip_atomic_store(p, v, __ATOMIC_RELAXED, __HIP_MEMORY_SCOPE_AGENT);
}
__device__ __forceinline__ void st_sysu(u32* p, u32 v){
  __hip_atomic_store(p, v, __ATOMIC_RELAXED, __HIP_MEMORY_SCOPE_AGENT);
}
__device__ __forceinline__ float ald(const float* p){
  return __hip_atomic_load(p, __ATOMIC_RELAXED, __HIP_MEMORY_SCOPE_AGENT);
}
__device__ __forceinline__ u32 aldu(const u32* p){
  return __hip_atomic_load(p, __ATOMIC_RELAXED, __HIP_MEMORY_SCOPE_AGENT);
}

__device__ __forceinline__ void vmwait0(){
  asm volatile("s_waitcnt vmcnt(0)" ::: "memory");
  __builtin_amdgcn_sched_barrier(0);
}
__device__ __forceinline__ void lgkm0(){
  asm volatile("s_waitcnt lgkmcnt(0)" ::: "memory");
  __builtin_amdgcn_sched_barrier(0);
}

// two-level arrive + two-level release grid barrier, epoch-based (r10 proven)
__device__ __forceinline__ void gsync(unsigned* bar, int w, unsigned& ep){
  ++ep;
  __builtin_amdgcn_s_waitcnt(0);
  __syncthreads();
  if (threadIdx.x == 0){
    const int g = w >> 4;
    const unsigned epoch = ep;
    bool rootfin = false;
    unsigned o = __hip_atomic_fetch_add(bar + g*32, 1u, __ATOMIC_ACQ_REL, __HIP_MEMORY_SCOPE_AGENT);
    if (o == 15u){
      __hip_atomic_store(bar + g*32, 0u, __ATOMIC_RELAXED, __HIP_MEMORY_SCOPE_AGENT);
      unsigned o2 = __hip_atomic_fetch_add(bar + 16*32, 1u, __ATOMIC_ACQ_REL, __HIP_MEMORY_SCOPE_AGENT);
      if (o2 == 15u){
        __hip_atomic_store(bar + 16*32, 0u, __ATOMIC_RELAXED, __HIP_MEMORY_SCOPE_AGENT);
        __hip_atomic_store(bar + 17*32, epoch, __ATOMIC_RELEASE, __HIP_MEMORY_SCOPE_AGENT);
        rootfin = true;
      }
    }
    if ((w & 15) == 0){
      if (!rootfin){
        while (__hip_atomic_load(bar + 17*32, __ATOMIC_RELAXED, __HIP_MEMORY_SCOPE_AGENT) < epoch)
          __builtin_amdgcn_s_sleep(1);
      }
      __hip_atomic_store(bar + (18+g)*32, epoch, __ATOMIC_RELEASE, __HIP_MEMORY_SCOPE_AGENT);
    } else {
      while (__hip_atomic_load(bar + (18+g)*32, __ATOMIC_RELAXED, __HIP_MEMORY_SCOPE_AGENT) < epoch)
        __builtin_amdgcn_s_sleep(1);
    }
  }
  __syncthreads();
}

// ---------------- LSTM layer: one-shot staging, 2 barriers total ----------
// Input = 64 rows x 512 u32 (1024 bf16). Stage whole input at once.
// Wave r owns gate-row wrow=((r&3)<<9)+(w<<1)+(r>>2); lane l owns k-slice
// u32 cols {l+64i, i=0..7} (k = 2(l+64i), 2(l+64i)+1). Within-wave reduce
// via wave-private LDS scratch (no s_barrier). Cell update by tid<128.

template<bool L0T>
__device__ __forceinline__ void lstm_layer(
    int w, int tid, const float (&wt)[8][2], const float (&wx)[4], float br,
    const u32* __restrict__ inu, float* sc_c,
    u32* __restrict__ dstA, int strA,
    u32* __restrict__ dstB, int strB,
    u32* stage, float* scr, u32* xsu, float* sG4,
    const float* __restrict__ tgt, int t)
{
  const int lane = tid & 63, r = tid >> 6;

  // x -> LDS as bf16 (L0 only; small, normal cached loads)
  if (L0T){
    #pragma unroll
    for (int i=0;i<5;++i){
      const int flat = tid + (i<<9);                 // < 2560
      const int row = flat/40, col = flat - row*40;
      const float* q = tgt + ((row<<8)+t)*80 + (col<<1);
      xsu[flat] = cvtpk(q[0], q[1]);
    }
  }
  // issue ALL 16 coalesced sc1 loads (128KB in flight), one exposed latency
  uint4 ld[16];
  #pragma unroll
  for (int i=0;i<16;++i){
    const u32* p = inu + (i<<11) + (tid<<2);
    asm volatile("global_load_dwordx4 %0, %1, off sc0 sc1" : "=v"(ld[i]) : "v"(p));
  }
  vmwait0();
  #pragma unroll
  for (int i=0;i<16;++i) *(uint4*)(stage + (i<<11) + (tid<<2)) = ld[i];
  __syncthreads();                                   // barrier 1: stage visible

  float* sw = scr + r*512;                           // wave-private scratch
  #pragma unroll 1
  for (int ch=0; ch<8; ++ch){
    float pv[8];
    #pragma unroll
    for (int bb=0; bb<8; ++bb){
      const u32* rowp = stage + ((ch<<3)+bb)*512 + lane;
      float a0=0.f,a1=0.f,a2=0.f,a3=0.f;
      #pragma unroll
      for (int i=0;i<8;i+=2){
        const u32 e0 = rowp[(i<<6)];
        const u32 e1 = rowp[((i+1)<<6)];
        a0 = fmaf(wt[i][0],   bflo(e0), a0);
        a1 = fmaf(wt[i][1],   bfhi(e0), a1);
        a2 = fmaf(wt[i+1][0], bflo(e1), a2);
        a3 = fmaf(wt[i+1][1], bfhi(e1), a3);
      }
      if (L0T && lane < 20){
        const u32 x0 = xsu[((ch<<3)+bb)*40 + (lane<<1)];
        const u32 x1 = xsu[((ch<<3)+bb)*40 + (lane<<1) + 1];
        a0 = fmaf(wx[0], bflo(x0), a0);
        a1 = fmaf(wx[1], bfhi(x0), a1);
        a2 = fmaf(wx[2], bflo(x1), a2);
        a3 = fmaf(wx[3], bfhi(x1), a3);
      }
      pv[bb] = (a0+a1)+(a2+a3);
    }
    // within-wave reduce (no s_barrier): 8 writes + 8 reads + 3 shuffles
    #pragma unroll
    for (int bb=0; bb<8; ++bb) sw[(bb<<6) + lane] = pv[bb];
    lgkm0();
    {
      const int bb2 = lane>>3, m = lane&7;
      const float* pp = sw + (bb2<<6) + (m<<3);
      float v = ((pp[0]+pp[1])+(pp[2]+pp[3])) + ((pp[4]+pp[5])+(pp[6]+pp[7]));
      v += __shfl_xor(v,1,64);
      v += __shfl_xor(v,2,64);
      v += __shfl_xor(v,4,64);
      if (m==0) sG4[((ch<<3)+bb2)*8 + r] = v + br;   // [b][row]
    }
  }
  lgkm0();
  __syncthreads();                                   // barrier 2: sG4 visible

  if (tid < 128){
    const int b = tid>>1, jl = tid&1;
    const float* g = sG4 + b*8 + (jl<<2);            // rows 4jl..4jl+3 = gates i,f,g,o
    const float gi = sigm(g[0]), gf = sigm(g[1]);
    const float gg = tanh_(g[2]), go = sigm(g[3]);
    const float cn = gf*sc_c[tid] + gi*gg;
    sc_c[tid] = cn;
    const float hn = go*tanh_(cn);
    const float hn1 = __shfl(hn, tid^1, 64);
    if (!(tid&1)){
      const u32 hp = cvtpk(hn, hn1);                 // (j=2w lo, 2w+1 hi)
      st_sysu(dstA + b*strA, hp);
      st_sysu(dstB + b*strB, hp);
    }
  }
}

// ---- ws layout (after 8KB barrier area), in UINTS (unchanged from r10) ----
#define ZERO_U   212992
#define FP_OFF   212992
#define ENC_OFF  475648
#define ENC_CNT  8388608

__global__ __launch_bounds__(NTHR, 2)
void sd_kernel(const float* __restrict__ tgt,  const float* __restrict__ enc,
               const int*   __restrict__ lens,
               const float* __restrict__ Wih0, const float* __restrict__ Whh0, const float* __restrict__ b0v,
               const float* __restrict__ Wih1, const float* __restrict__ Whh1, const float* __restrict__ b1v,
               const float* __restrict__ Wih2, const float* __restrict__ Whh2, const float* __restrict__ b2v,
               const float* __restrict__ Wq,   const float* __restrict__ Wfc,  const float* __restrict__ bfc,
               float* __restrict__ out, void* __restrict__ wsv, int ebf)
{
  unsigned* bar = (unsigned*)wsv;
  u32* wsu = (u32*)((char*)wsv + 8192);
  u32* IN0u = wsu;
  u32* IN1u = wsu + 65536;
  u32* IN2u = wsu + 131072;
  u32* H2u  = wsu + 196608;
  float* F  = (float*)(wsu + FP_OFF);
  float* QP = F;
  float* PC = F + 131072;
  float* MS = F + 262144;
  u32* encbfu = wsu + ENC_OFF;

  const int w = blockIdx.x, tid = threadIdx.x;
  const int lane = tid & 63, r = tid >> 6;
  unsigned ep = 0;

  // one shared block, manually laid out (161,280 B of 160 KiB):
  __shared__ __attribute__((aligned(16))) u32 SM[40320];
  u32*   stage = SM;                       // 32768 u32 = 128KB  (LSTM input)
  float* scr   = (float*)(SM + 32768);     // 4096 f = 16KB      (wave reduce)
  u32*   xsu   = SM + 36864;               // 2560 u32 = 10KB    (L0 x bf16)
  float* sG4   = (float*)(SM + 39424);     // 512 f              (gates [b][row])
  float* sc_c  = (float*)(SM + 39936);     // 384 f              (cells/layer)
  // attn aliases into stage region (phases disjoint, gsync between):
  float* sBig   = (float*)SM;              // 4096 f
  float* sVec   = (float*)(SM + 4096);     // 512 f
  float* sSmall = (float*)(SM + 4608);     // 16 f

  // ---- prologue: weights -> registers (normal cached) ----
  const int wrow = ((r&3)<<9) + (w<<1) + (r>>2);
  float w0r[8][2], w1r[8][2], w2r[8][2], wx0[4];
  #pragma unroll
  for (int i=0;i<8;++i){
    const int k = 2*(lane + (i<<6));
    if (k < 512){
      w0r[i][0] = Wih0[wrow*592 + 80 + k];
      w0r[i][1] = Wih0[wrow*592 + 80 + k + 1];
      w1r[i][0] = Wih1[(wrow<<9) + k];
      w1r[i][1] = Wih1[(wrow<<9) + k + 1];
      w2r[i][0] = Wih2[(wrow<<9) + k];
      w2r[i][1] = Wih2[(wrow<<9) + k + 1];
    } else {
      w0r[i][0] = Whh0[(wrow<<9) + k - 512];
      w0r[i][1] = Whh0[(wrow<<9) + k - 511];
      w1r[i][0] = Whh1[(wrow<<9) + k - 512];
      w1r[i][1] = Whh1[(wrow<<9) + k - 511];
      w2r[i][0] = Whh2[(wrow<<9) + k - 512];
      w2r[i][1] = Whh2[(wrow<<9) + k - 511];
    }
  }
  #pragma unroll
  for (int m=0;m<4;++m)
    wx0[m] = (lane < 20) ? Wih0[wrow*592 + (lane<<2) + m] : 0.f;
  const float br0 = b0v[wrow], br1 = b1v[wrow], br2 = b2v[wrow];

  if (tid < 384) sc_c[tid] = 0.f;
  for (int i = w*NTHR + tid; i < ZERO_U; i += NBLK*NTHR) st_sysu(wsu + i, 0u);
  if (ebf){
    for (int i = w*NTHR + tid; i < ENC_CNT; i += NBLK*NTHR)
      st_sysu(encbfu + i, cvtpk(enc[2*i], enc[2*i+1]));
  }
  gsync(bar, w, ep);

  for (int t=0; t<255; ++t){
    const int p = t & 1, np = p ^ 1;
    u32* IN0p = IN0u + p*32768;  u32* IN0n = IN0u + np*32768;
    u32* IN1p = IN1u + p*32768;  u32* IN1n = IN1u + np*32768;
    u32* IN2p = IN2u + p*32768;  u32* IN2n = IN2u + np*32768;

    lstm_layer<true >(w,tid, w0r, wx0, br0, IN0p, sc_c,
                      IN0n+256+w, 512, IN1p+w, 512, stage,scr,xsu,sG4, tgt, t);
    gsync(bar,w,ep);
    lstm_layer<false>(w,tid, w1r, wx0, br1, IN1p, sc_c+128,
                      IN1n+256+w, 512, IN2p+w, 512, stage,scr,xsu,sG4, tgt, t);
    gsync(bar,w,ep);
    lstm_layer<false>(w,tid, w2r, wx0, br2, IN2p, sc_c+256,
                      IN2n+256+w, 512, H2u+w, 256, stage,scr,xsu,sG4, tgt, t);
    gsync(bar,w,ep);

    // ---- q partials: WG (b = w&63, kq = w>>6) over k-quarter ----
    {
      const int b = w & 63, kq = w >> 6;
      if (tid < 64){
        const u32 u = aldu(H2u + b*256 + kq*64 + tid);
        sVec[2*tid]   = bflo(u);
        sVec[2*tid+1] = bfhi(u);
      }
      __syncthreads();
      const float* wqp = Wq + ((size_t)(kq<<7)<<9) + tid;
      float acc = 0.f;
      #pragma unroll 4
      for (int k=0;k<128;++k) acc = fmaf(sVec[k], wqp[(size_t)k<<9], acc);
      st_sys(&QP[(((kq<<6)+b)<<9) + tid], acc);
    }
    gsync(bar,w,ep);

    // ---- attention A: WG (b, sq): online-softmax over 128 enc rows ----
    {
      const int b = w & 63, sq = w >> 6;
      const int len  = lens[b];
      const int wv = tid >> 6;
      sVec[tid] = ald(&QP[(b<<9)+tid]) + ald(&QP[((64+b)<<9)+tid])
                + ald(&QP[((128+b)<<9)+tid]) + ald(&QP[((192+b)<<9)+tid]);
      __syncthreads();
      const float4 qA = *(const float4*)(sVec + (lane<<3));
      const float4 qB = *(const float4*)(sVec + (lane<<3) + 4);
      float mr = -3.0e38f, lr = 0.f;
      float c0=0,c1=0,c2=0,c3=0,c4=0,c5=0,c6=0,c7=0;
      const float scale = 0.04419417382415922f;
      if (ebf){
        const u32* ebase = encbfu + (((size_t)b)<<17) + (lane<<2);
        #pragma unroll 1
        for (int rr=0; rr<16; ++rr){
          const int srow = (sq<<7) + (wv<<4) + rr;
          if (srow >= len) break;
          const uint4 eu = *(const uint4*)(ebase + ((size_t)srow<<8));
          const float e0=bflo(eu.x), e1=bfhi(eu.x), e2=bflo(eu.y), e3=bfhi(eu.y);
          const float e4=bflo(eu.z), e5=bfhi(eu.z), e6=bflo(eu.w), e7=bfhi(eu.w);
          float d0 = qA.x*e0, d1 = qA.y*e1, d2 = qA.z*e2, d3 = qA.w*e3;
          d0 = fmaf(qB.x, e4, d0); d1 = fmaf(qB.y, e5, d1);
          d2 = fmaf(qB.z, e6, d2); d3 = fmaf(qB.w, e7, d3);
          float d = wred_sum((d0+d1)+(d2+d3));
          const float sc = d*scale;
          const float mn = fmaxf(mr, sc);
          const float sf = __expf(mr - mn);
          const float pe = __expf(sc - mn);
          lr = fmaf(lr, sf, pe);
          c0 = fmaf(c0, sf, pe*e0); c1 = fmaf(c1, sf, pe*e1);
          c2 = fmaf(c2, sf, pe*e2); c3 = fmaf(c3, sf, pe*e3);
          c4 = fmaf(c4, sf, pe*e4); c5 = fmaf(c5, sf, pe*e5);
          c6 = fmaf(c6, sf, pe*e6); c7 = fmaf(c7, sf, pe*e7);
          mr = mn;
        }
      } else {
        #pragma unroll 1
        for (int rr=0; rr<16; ++rr){
          const int srow = (sq<<7) + (wv<<4) + rr;
          if (srow >= len) break;
          const float* ep2 = enc + (((size_t)(b<<9)+srow)<<9) + (lane<<3);
          const float4 e0v = *(const float4*)(ep2);
          const float4 e1v = *(const float4*)(ep2+4);
          float d0 = qA.x*e0v.x, d1 = qA.y*e0v.y, d2 = qA.z*e0v.z, d3 = qA.w*e0v.w;
          d0 = fmaf(qB.x, e1v.x, d0); d1 = fmaf(qB.y, e1v.y, d1);
          d2 = fmaf(qB.z, e1v.z, d2); d3 = fmaf(qB.w, e1v.w, d3);
          float d = wred_sum((d0+d1)+(d2+d3));
          const float sc = d*scale;
          const float mn = fmaxf(mr, sc);
          const float sf = __expf(mr - mn);
          const float pe = __expf(sc - mn);
          lr = fmaf(lr, sf, pe);
          c0 = fmaf(c0, sf, pe*e0v.x); c1 = fmaf(c1, sf, pe*e0v.y);
          c2 = fmaf(c2, sf, pe*e0v.z); c3 = fmaf(c3, sf, pe*e0v.w);
          c4 = fmaf(c4, sf, pe*e1v.x); c5 = fmaf(c5, sf, pe*e1v.y);
          c6 = fmaf(c6, sf, pe*e1v.z); c7 = fmaf(c7, sf, pe*e1v.w);
          mr = mn;
        }
      }
      if (lane==0){ sSmall[wv] = mr; sSmall[8+wv] = lr; }
      {
        float4 v0 = {c0,c1,c2,c3}, v1 = {c4,c5,c6,c7};
        *(float4*)(sBig + (wv<<9) + (lane<<3))     = v0;
        *(float4*)(sBig + (wv<<9) + (lane<<3) + 4) = v1;
      }
      __syncthreads();
      float M = sSmall[0];
      #pragma unroll
      for (int i=1;i<8;++i) M = fmaxf(M, sSmall[i]);
      float L = 0.f, acc = 0.f;
      #pragma unroll
      for (int i=0;i<8;++i){
        const float A = __expf(sSmall[i]-M);
        L   = fmaf(A, sSmall[8+i], L);
        acc = fmaf(A, sBig[(i<<9)+tid], acc);
      }
      st_sys(&PC[(((sq<<6)+b)<<9)+tid], acc);
      if (tid==0){
        st_sys(&MS[(((sq<<6)+b)<<1)],   M);
        st_sys(&MS[(((sq<<6)+b)<<1)+1], L);
      }
    }
    gsync(bar,w,ep);

    // ---- attention B: combine + FC + out (WGs 0..63 only) ----
    if (w < 64){
      const int b = w;
      const float m0 = ald(&MS[(b)<<1]),      S0 = ald(&MS[((b)<<1)+1]);
      const float m1 = ald(&MS[(64+b)<<1]),   S1 = ald(&MS[((64+b)<<1)+1]);
      const float m2 = ald(&MS[(128+b)<<1]),  S2 = ald(&MS[((128+b)<<1)+1]);
      const float m3 = ald(&MS[(192+b)<<1]),  S3 = ald(&MS[((192+b)<<1)+1]);
      const float M  = fmaxf(fmaxf(m0,m1), fmaxf(m2,m3));
      const float a0=__expf(m0-M), a1=__expf(m1-M), a2=__expf(m2-M), a3=__expf(m3-M);
      const float inv = 1.f/(a0*S0 + a1*S1 + a2*S2 + a3*S3);
      const float c = (a0*ald(&PC[(b<<9)+tid])       + a1*ald(&PC[((64+b)<<9)+tid])
                     + a2*ald(&PC[((128+b)<<9)+tid]) + a3*ald(&PC[((192+b)<<9)+tid])) * inv;
      const float c1 = __shfl(c, tid^1, 64);
      if (!(tid&1)) st_sysu(IN0n + b*512 + (tid>>1), cvtpk(c, c1));
      sVec[tid] = c;
      __syncthreads();
      if (tid < 80){
        float acc = 0.f;
        #pragma unroll 4
        for (int e2=0;e2<512;++e2) acc = fmaf(sVec[e2], Wfc[e2*80+tid], acc);
        out[((size_t)b*255 + t)*80 + tid] = acc + bfc[tid];
      }
    }
    gsync(bar,w,ep);
  }
}

extern "C" void kernel_launch(void* const* d_in, const int* in_sizes, int n_in,
                              void* d_out, int out_size, void* d_ws, size_t ws_size,
                              hipStream_t stream) {
  const float* tgt  = (const float*)d_in[0];
  const float* enc  = (const float*)d_in[1];
  const int*   lens = (const int*)  d_in[2];
  const float* Wih0 = (const float*)d_in[3];
  const float* Whh0 = (const float*)d_in[4];
  const float* b0   = (const float*)d_in[5];
  const float* Wih1 = (const float*)d_in[6];
  const float* Whh1 = (const float*)d_in[7];
  const float* b1   = (const float*)d_in[8];
  const float* Wih2 = (const float*)d_in[9];
  const float* Whh2 = (const float*)d_in[10];
  const float* b2   = (const float*)d_in[11];
  const float* Wq   = (const float*)d_in[12];
  const float* Wfc  = (const float*)d_in[13];
  const float* bfc  = (const float*)d_in[14];

  const size_t need = 8192ull + ((size_t)ENC_OFF + (size_t)ENC_CNT)*4ull;
  const int ebf = (ws_size >= need) ? 1 : 0;

  hipMemsetAsync(d_ws, 0, 8192, stream);   // barrier counters
  sd_kernel<<<NBLK, NTHR, 0, stream>>>(tgt, enc, lens,
                                       Wih0, Whh0, b0,
                                       Wih1, Whh1, b1,
                                       Wih2, Whh2, b2,
                                       Wq, Wfc, bfc,
                                       (float*)d_out, d_ws, ebf);
}

// Round 13
// 30511.813 us; speedup vs baseline: 1.4430x; 1.0931x over previous
//
#include <hip/hip_runtime.h>

#define NBLK 256
#define NTHR 512

typedef float f32x4 __attribute__((ext_vector_type(4)));
typedef unsigned int u32;

// ---------------- math helpers ----------------
__device__ __forceinline__ float sigm(float x){ return 1.f/(1.f+__expf(-x)); }
__device__ __forceinline__ float tanh_(float x){ return 1.f - 2.f/(__expf(2.f*x)+1.f); }

__device__ __forceinline__ float wred_sum(float v){
  #pragma unroll
  for (int off=32; off; off>>=1) v += __shfl_xor(v, off, 64);
  return v;
}

// bf16 pack/unpack
__device__ __forceinline__ u32 cvtpk(float lo, float hi){
  u32 r; asm("v_cvt_pk_bf16_f32 %0,%1,%2":"=v"(r):"v"(lo),"v"(hi)); return r;
}
__device__ __forceinline__ float bflo(u32 u){ return __uint_as_float(u<<16); }
__device__ __forceinline__ float bfhi(u32 u){ return __uint_as_float(u & 0xFFFF0000u); }

// agent-coherent (sc1) store/load
__device__ __forceinline__ void st_sys(float* p, float v){
  __hip_atomic_store(p, v, __ATOMIC_RELAXED, __HIP_MEMORY_SCOPE_AGENT);
}
__device__ __forceinline__ void st_sysu(u32* p, u32 v){
  __hip_atomic_store(p, v, __ATOMIC_RELAXED, __HIP_MEMORY_SCOPE_AGENT);
}
__device__ __forceinline__ float ald(const float* p){
  return __hip_atomic_load(p, __ATOMIC_RELAXED, __HIP_MEMORY_SCOPE_AGENT);
}
__device__ __forceinline__ u32 aldu(const u32* p){
  return __hip_atomic_load(p, __ATOMIC_RELAXED, __HIP_MEMORY_SCOPE_AGENT);
}

__device__ __forceinline__ void vmwait0(){
  asm volatile("s_waitcnt vmcnt(0)" ::: "memory");
  __builtin_amdgcn_sched_barrier(0);
}
__device__ __forceinline__ void lgkm0(){
  asm volatile("s_waitcnt lgkmcnt(0)" ::: "memory");
  __builtin_amdgcn_sched_barrier(0);
}

// two-level arrive + two-level release grid barrier, epoch-based (proven)
__device__ __forceinline__ void gsync(unsigned* bar, int w, unsigned& ep){
  ++ep;
  __builtin_amdgcn_s_waitcnt(0);
  __syncthreads();
  if (threadIdx.x == 0){
    const int g = w >> 4;
    const unsigned epoch = ep;
    bool rootfin = false;
    unsigned o = __hip_atomic_fetch_add(bar + g*32, 1u, __ATOMIC_ACQ_REL, __HIP_MEMORY_SCOPE_AGENT);
    if (o == 15u){
      __hip_atomic_store(bar + g*32, 0u, __ATOMIC_RELAXED, __HIP_MEMORY_SCOPE_AGENT);
      unsigned o2 = __hip_atomic_fetch_add(bar + 16*32, 1u, __ATOMIC_ACQ_REL, __HIP_MEMORY_SCOPE_AGENT);
      if (o2 == 15u){
        __hip_atomic_store(bar + 16*32, 0u, __ATOMIC_RELAXED, __HIP_MEMORY_SCOPE_AGENT);
        __hip_atomic_store(bar + 17*32, epoch, __ATOMIC_RELEASE, __HIP_MEMORY_SCOPE_AGENT);
        rootfin = true;
      }
    }
    if ((w & 15) == 0){
      if (!rootfin){
        while (__hip_atomic_load(bar + 17*32, __ATOMIC_RELAXED, __HIP_MEMORY_SCOPE_AGENT) < epoch)
          __builtin_amdgcn_s_sleep(1);
      }
      __hip_atomic_store(bar + (18+g)*32, epoch, __ATOMIC_RELEASE, __HIP_MEMORY_SCOPE_AGENT);
    } else {
      while (__hip_atomic_load(bar + (18+g)*32, __ATOMIC_RELAXED, __HIP_MEMORY_SCOPE_AGENT) < epoch)
        __builtin_amdgcn_s_sleep(1);
    }
  }
  __syncthreads();
}

// ---------------- LSTM layer: (jt,bt) = 128x2 tiling -----------------------
// WG (jt = w>>1, bt = w&1): 16 gate-rows (j = 4jt..4jt+3, 4 gates) x 32 batches.
// Wave r computes rows rho = r and r+8 (wrow2 = wrow1 + 2). Lane l owns u32
// k-cols {l+64i, i<8}. Stage = 32 rows x 512 u32 (64 KB), one-shot sc1 load.
// Reduce via wave-private scratch (1024 f), no s_barrier. Cells: 32 b x 4 j.

template<bool L0T>
__device__ __forceinline__ void lstm_layer(
    int jt, int bt, int tid,
    const float (&wt)[2][8][2], const float (&wx)[2][4],
    float brA, float brB,
    const u32* __restrict__ inu, float* sc_c,
    u32* __restrict__ dstA, int strA,
    u32* __restrict__ dstB, int strB,
    u32* stage, float* scr, u32* xsu, float* sG4,
    const float* __restrict__ tgt, int t)
{
  const int lane = tid & 63, r = tid >> 6;
  const u32* src = inu + bt*16384;

  if (L0T){
    #pragma unroll
    for (int i=0;i<3;++i){
      const int flat = tid + (i<<9);
      if (flat < 1280){
        const int row = flat/40, col = flat - row*40;
        const float* q = tgt + ((((bt<<5)+row)<<8) + t)*80 + (col<<1);
        xsu[flat] = cvtpk(q[0], q[1]);
      }
    }
  }
  // one-shot coalesced sc1 stage: 8 x dwordx4 per thread (64 KB total)
  uint4 ld[8];
  #pragma unroll
  for (int i=0;i<8;++i){
    const u32* p = src + (i<<11) + (tid<<2);
    asm volatile("global_load_dwordx4 %0, %1, off sc0 sc1" : "=v"(ld[i]) : "v"(p));
  }
  vmwait0();
  #pragma unroll
  for (int i=0;i<8;++i) *(uint4*)(stage + (i<<11) + (tid<<2)) = ld[i];
  __syncthreads();                                   // barrier 1: stage visible

  float* sw = scr + r*1024;                          // wave-private scratch
  #pragma unroll 1
  for (int ch=0; ch<4; ++ch){
    float pv0[8], pv1[8];
    #pragma unroll
    for (int bb=0; bb<8; ++bb){
      const u32* rowp = stage + ((ch<<3)+bb)*512 + lane;
      float a0=0.f,a1=0.f,a2=0.f,a3=0.f, c0=0.f,c1=0.f,c2=0.f,c3=0.f;
      #pragma unroll
      for (int i=0;i<8;i+=2){
        const u32 e0 = rowp[(i<<6)];
        const u32 e1 = rowp[((i+1)<<6)];
        const float f0=bflo(e0), f1=bfhi(e0), f2=bflo(e1), f3=bfhi(e1);
        a0 = fmaf(wt[0][i][0],   f0, a0);
        a1 = fmaf(wt[0][i][1],   f1, a1);
        a2 = fmaf(wt[0][i+1][0], f2, a2);
        a3 = fmaf(wt[0][i+1][1], f3, a3);
        c0 = fmaf(wt[1][i][0],   f0, c0);
        c1 = fmaf(wt[1][i][1],   f1, c1);
        c2 = fmaf(wt[1][i+1][0], f2, c2);
        c3 = fmaf(wt[1][i+1][1], f3, c3);
      }
      if (L0T && lane < 20){
        const int lrow = (ch<<3)+bb;
        const u32 x0 = xsu[lrow*40 + (lane<<1)];
        const u32 x1 = xsu[lrow*40 + (lane<<1) + 1];
        const float g0=bflo(x0), g1=bfhi(x0), g2=bflo(x1), g3=bfhi(x1);
        a0 = fmaf(wx[0][0], g0, a0); a1 = fmaf(wx[0][1], g1, a1);
        a2 = fmaf(wx[0][2], g2, a2); a3 = fmaf(wx[0][3], g3, a3);
        c0 = fmaf(wx[1][0], g0, c0); c1 = fmaf(wx[1][1], g1, c1);
        c2 = fmaf(wx[1][2], g2, c2); c3 = fmaf(wx[1][3], g3, c3);
      }
      pv0[bb] = (a0+a1)+(a2+a3);
      pv1[bb] = (c0+c1)+(c2+c3);
    }
    #pragma unroll
    for (int bb=0; bb<8; ++bb){
      sw[(bb<<6) + lane]       = pv0[bb];
      sw[512 + (bb<<6) + lane] = pv1[bb];
    }
    lgkm0();
    {
      const int bb2 = lane>>3, m = lane&7;
      const float* pp = sw + (bb2<<6) + (m<<3);
      float v0 = ((pp[0]+pp[1])+(pp[2]+pp[3])) + ((pp[4]+pp[5])+(pp[6]+pp[7]));
      const float* pq = pp + 512;
      float v1 = ((pq[0]+pq[1])+(pq[2]+pq[3])) + ((pq[4]+pq[5])+(pq[6]+pq[7]));
      v0 += __shfl_xor(v0,1,64); v0 += __shfl_xor(v0,2,64); v0 += __shfl_xor(v0,4,64);
      v1 += __shfl_xor(v1,1,64); v1 += __shfl_xor(v1,2,64); v1 += __shfl_xor(v1,4,64);
      if (m==0){
        sG4[(((ch<<3)+bb2)<<4) + r]     = v0 + brA;   // row rho = r
        sG4[(((ch<<3)+bb2)<<4) + r + 8] = v1 + brB;   // row rho = r+8
      }
    }
  }
  lgkm0();
  __syncthreads();                                   // barrier 2: sG4 visible

  if (tid < 128){
    const int b = tid>>2, jl = tid&3;                // local batch, local j
    const float* g = sG4 + (b<<4) + (jl<<2);         // gates i,f,g,o at 4jl+0..3
    const float gi = sigm(g[0]), gf = sigm(g[1]);
    const float gg = tanh_(g[2]), go = sigm(g[3]);
    const float cn = gf*sc_c[tid] + gi*gg;
    sc_c[tid] = cn;
    const float hn = go*tanh_(cn);
    const float hn1 = __shfl(hn, tid^1, 64);
    if (!(tid&1)){
      const u32 hp = cvtpk(hn, hn1);                 // (j even, j odd) packed
      const int gb = (bt<<5) + b;
      const int col = (jt<<1) + (jl>>1);
      st_sysu(dstA + gb*strA + col, hp);
      st_sysu(dstB + gb*strB + col, hp);
    }
  }
}

// ---- ws layout (after 8KB barrier area), in UINTS (unchanged) ----
#define ZERO_U   212992
#define FP_OFF   212992
#define ENC_OFF  475648
#define ENC_CNT  8388608

__global__ __launch_bounds__(NTHR, 2)
void sd_kernel(const float* __restrict__ tgt,  const float* __restrict__ enc,
               const int*   __restrict__ lens,
               const float* __restrict__ Wih0, const float* __restrict__ Whh0, const float* __restrict__ b0v,
               const float* __restrict__ Wih1, const float* __restrict__ Whh1, const float* __restrict__ b1v,
               const float* __restrict__ Wih2, const float* __restrict__ Whh2, const float* __restrict__ b2v,
               const float* __restrict__ Wq,   const float* __restrict__ Wfc,  const float* __restrict__ bfc,
               float* __restrict__ out, void* __restrict__ wsv, int ebf)
{
  unsigned* bar = (unsigned*)wsv;
  u32* wsu = (u32*)((char*)wsv + 8192);
  u32* IN0u = wsu;
  u32* IN1u = wsu + 65536;
  u32* IN2u = wsu + 131072;
  u32* H2u  = wsu + 196608;
  float* F  = (float*)(wsu + FP_OFF);
  float* QP = F;
  float* PC = F + 131072;
  float* MS = F + 262144;
  u32* encbfu = wsu + ENC_OFF;

  const int w = blockIdx.x, tid = threadIdx.x;
  const int lane = tid & 63, r = tid >> 6;
  const int jt = w >> 1, bt = w & 1;
  unsigned ep = 0;

  // LDS: stage 16384u | scr 8192f | xsu 1280u | sG4 512f | sc_c 384f = ~107KB
  __shared__ __attribute__((aligned(16))) u32 SM[26752];
  u32*   stage = SM;
  float* scr   = (float*)(SM + 16384);
  u32*   xsu   = SM + 24576;
  float* sG4   = (float*)(SM + 25856);
  float* sc_c  = (float*)(SM + 26368);
  // attn aliases into stage region (disjoint phases):
  float* sBig   = (float*)SM;              // 4096 f
  float* sVec   = (float*)(SM + 4096);     // 512 f
  float* sSmall = (float*)(SM + 4608);     // 16 f

  // ---- prologue: weights -> registers (2 rows per wave) ----
  const int wrowA = ((r&3)<<9) + (jt<<2) + (r>>2);
  const int wrowB = wrowA + 2;
  float w0r[2][8][2], w1r[2][8][2], w2r[2][8][2], wx0[2][4];
  #pragma unroll
  for (int s=0;s<2;++s){
    const int wr = s ? wrowB : wrowA;
    #pragma unroll
    for (int i=0;i<8;++i){
      const int k = 2*(lane + (i<<6));
      if (k < 512){
        w0r[s][i][0] = Wih0[wr*592 + 80 + k];   w0r[s][i][1] = Wih0[wr*592 + 81 + k];
        w1r[s][i][0] = Wih1[(wr<<9) + k];       w1r[s][i][1] = Wih1[(wr<<9) + k + 1];
        w2r[s][i][0] = Wih2[(wr<<9) + k];       w2r[s][i][1] = Wih2[(wr<<9) + k + 1];
      } else {
        w0r[s][i][0] = Whh0[(wr<<9) + k - 512]; w0r[s][i][1] = Whh0[(wr<<9) + k - 511];
        w1r[s][i][0] = Whh1[(wr<<9) + k - 512]; w1r[s][i][1] = Whh1[(wr<<9) + k - 511];
        w2r[s][i][0] = Whh2[(wr<<9) + k - 512]; w2r[s][i][1] = Whh2[(wr<<9) + k - 511];
      }
    }
    #pragma unroll
    for (int m=0;m<4;++m)
      wx0[s][m] = (lane < 20) ? Wih0[wr*592 + (lane<<2) + m] : 0.f;
  }
  const float br0A=b0v[wrowA], br0B=b0v[wrowB];
  const float br1A=b1v[wrowA], br1B=b1v[wrowB];
  const float br2A=b2v[wrowA], br2B=b2v[wrowB];

  if (tid < 384) sc_c[tid] = 0.f;
  for (int i = w*NTHR + tid; i < ZERO_U; i += NBLK*NTHR) st_sysu(wsu + i, 0u);
  if (ebf){
    for (int i = w*NTHR + tid; i < ENC_CNT; i += NBLK*NTHR)
      st_sysu(encbfu + i, cvtpk(enc[2*i], enc[2*i+1]));
  }
  gsync(bar, w, ep);

  for (int t=0; t<255; ++t){
    const int p = t & 1, np = p ^ 1;
    u32* IN0p = IN0u + p*32768;  u32* IN0n = IN0u + np*32768;
    u32* IN1p = IN1u + p*32768;  u32* IN1n = IN1u + np*32768;
    u32* IN2p = IN2u + p*32768;  u32* IN2n = IN2u + np*32768;

    lstm_layer<true >(jt,bt,tid, w0r, wx0, br0A, br0B, IN0p, sc_c,
                      IN0n+256, 512, IN1p, 512, stage,scr,xsu,sG4, tgt, t);
    gsync(bar,w,ep);
    lstm_layer<false>(jt,bt,tid, w1r, wx0, br1A, br1B, IN1p, sc_c+128,
                      IN1n+256, 512, IN2p, 512, stage,scr,xsu,sG4, tgt, t);
    gsync(bar,w,ep);
    lstm_layer<false>(jt,bt,tid, w2r, wx0, br2A, br2B, IN2p, sc_c+256,
                      IN2n+256, 512, H2u, 256, stage,scr,xsu,sG4, tgt, t);
    gsync(bar,w,ep);

    // ---- q partials: WG (b = w&63, kq = w>>6) over k-quarter ----
    {
      const int b = w & 63, kq = w >> 6;
      if (tid < 64){
        const u32 u = aldu(H2u + b*256 + kq*64 + tid);
        sVec[2*tid]   = bflo(u);
        sVec[2*tid+1] = bfhi(u);
      }
      __syncthreads();
      const float* wqp = Wq + ((size_t)(kq<<7)<<9) + tid;
      float acc = 0.f;
      #pragma unroll 4
      for (int k=0;k<128;++k) acc = fmaf(sVec[k], wqp[(size_t)k<<9], acc);
      st_sys(&QP[(((kq<<6)+b)<<9) + tid], acc);
    }
    gsync(bar,w,ep);

    // ---- attention A: WG (b, sq): online-softmax over 128 enc rows ----
    {
      const int b = w & 63, sq = w >> 6;
      const int len  = lens[b];
      const int wv = tid >> 6;
      sVec[tid] = ald(&QP[(b<<9)+tid]) + ald(&QP[((64+b)<<9)+tid])
                + ald(&QP[((128+b)<<9)+tid]) + ald(&QP[((192+b)<<9)+tid]);
      __syncthreads();
      const float4 qA = *(const float4*)(sVec + (lane<<3));
      const float4 qB = *(const float4*)(sVec + (lane<<3) + 4);
      float mr = -3.0e38f, lr = 0.f;
      float c0=0,c1=0,c2=0,c3=0,c4=0,c5=0,c6=0,c7=0;
      const float scale = 0.04419417382415922f;
      if (ebf){
        const u32* ebase = encbfu + (((size_t)b)<<17) + (lane<<2);
        #pragma unroll 1
        for (int rr=0; rr<16; ++rr){
          const int srow = (sq<<7) + (wv<<4) + rr;
          if (srow >= len) break;
          const uint4 eu = *(const uint4*)(ebase + ((size_t)srow<<8));
          const float e0=bflo(eu.x), e1=bfhi(eu.x), e2=bflo(eu.y), e3=bfhi(eu.y);
          const float e4=bflo(eu.z), e5=bfhi(eu.z), e6=bflo(eu.w), e7=bfhi(eu.w);
          float d0 = qA.x*e0, d1 = qA.y*e1, d2 = qA.z*e2, d3 = qA.w*e3;
          d0 = fmaf(qB.x, e4, d0); d1 = fmaf(qB.y, e5, d1);
          d2 = fmaf(qB.z, e6, d2); d3 = fmaf(qB.w, e7, d3);
          float d = wred_sum((d0+d1)+(d2+d3));
          const float sc = d*scale;
          const float mn = fmaxf(mr, sc);
          const float sf = __expf(mr - mn);
          const float pe = __expf(sc - mn);
          lr = fmaf(lr, sf, pe);
          c0 = fmaf(c0, sf, pe*e0); c1 = fmaf(c1, sf, pe*e1);
          c2 = fmaf(c2, sf, pe*e2); c3 = fmaf(c3, sf, pe*e3);
          c4 = fmaf(c4, sf, pe*e4); c5 = fmaf(c5, sf, pe*e5);
          c6 = fmaf(c6, sf, pe*e6); c7 = fmaf(c7, sf, pe*e7);
          mr = mn;
        }
      } else {
        #pragma unroll 1
        for (int rr=0; rr<16; ++rr){
          const int srow = (sq<<7) + (wv<<4) + rr;
          if (srow >= len) break;
          const float* ep2 = enc + (((size_t)(b<<9)+srow)<<9) + (lane<<3);
          const float4 e0v = *(const float4*)(ep2);
          const float4 e1v = *(const float4*)(ep2+4);
          float d0 = qA.x*e0v.x, d1 = qA.y*e0v.y, d2 = qA.z*e0v.z, d3 = qA.w*e0v.w;
          d0 = fmaf(qB.x, e1v.x, d0); d1 = fmaf(qB.y, e1v.y, d1);
          d2 = fmaf(qB.z, e1v.z, d2); d3 = fmaf(qB.w, e1v.w, d3);
          float d = wred_sum((d0+d1)+(d2+d3));
          const float sc = d*scale;
          const float mn = fmaxf(mr, sc);
          const float sf = __expf(mr - mn);
          const float pe = __expf(sc - mn);
          lr = fmaf(lr, sf, pe);
          c0 = fmaf(c0, sf, pe*e0v.x); c1 = fmaf(c1, sf, pe*e0v.y);
          c2 = fmaf(c2, sf, pe*e0v.z); c3 = fmaf(c3, sf, pe*e0v.w);
          c4 = fmaf(c4, sf, pe*e1v.x); c5 = fmaf(c5, sf, pe*e1v.y);
          c6 = fmaf(c6, sf, pe*e1v.z); c7 = fmaf(c7, sf, pe*e1v.w);
          mr = mn;
        }
      }
      if (lane==0){ sSmall[wv] = mr; sSmall[8+wv] = lr; }
      {
        float4 v0 = {c0,c1,c2,c3}, v1 = {c4,c5,c6,c7};
        *(float4*)(sBig + (wv<<9) + (lane<<3))     = v0;
        *(float4*)(sBig + (wv<<9) + (lane<<3) + 4) = v1;
      }
      __syncthreads();
      float M = sSmall[0];
      #pragma unroll
      for (int i=1;i<8;++i) M = fmaxf(M, sSmall[i]);
      float L = 0.f, acc = 0.f;
      #pragma unroll
      for (int i=0;i<8;++i){
        const float A = __expf(sSmall[i]-M);
        L   = fmaf(A, sSmall[8+i], L);
        acc = fmaf(A, sBig[(i<<9)+tid], acc);
      }
      st_sys(&PC[(((sq<<6)+b)<<9)+tid], acc);
      if (tid==0){
        st_sys(&MS[(((sq<<6)+b)<<1)],   M);
        st_sys(&MS[(((sq<<6)+b)<<1)+1], L);
      }
    }
    gsync(bar,w,ep);

    // ---- attention B: combine + FC + out (WGs 0..63 only) ----
    if (w < 64){
      const int b = w;
      const float m0 = ald(&MS[(b)<<1]),      S0 = ald(&MS[((b)<<1)+1]);
      const float m1 = ald(&MS[(64+b)<<1]),   S1 = ald(&MS[((64+b)<<1)+1]);
      const float m2 = ald(&MS[(128+b)<<1]),  S2 = ald(&MS[((128+b)<<1)+1]);
      const float m3 = ald(&MS[(192+b)<<1]),  S3 = ald(&MS[((192+b)<<1)+1]);
      const float M  = fmaxf(fmaxf(m0,m1), fmaxf(m2,m3));
      const float a0=__expf(m0-M), a1=__expf(m1-M), a2=__expf(m2-M), a3=__expf(m3-M);
      const float inv = 1.f/(a0*S0 + a1*S1 + a2*S2 + a3*S3);
      const float c = (a0*ald(&PC[(b<<9)+tid])       + a1*ald(&PC[((64+b)<<9)+tid])
                     + a2*ald(&PC[((128+b)<<9)+tid]) + a3*ald(&PC[((192+b)<<9)+tid])) * inv;
      const float c1 = __shfl(c, tid^1, 64);
      if (!(tid&1)) st_sysu(IN0n + b*512 + (tid>>1), cvtpk(c, c1));
      sVec[tid] = c;
      __syncthreads();
      if (tid < 80){
        float acc = 0.f;
        #pragma unroll 4
        for (int e2=0;e2<512;++e2) acc = fmaf(sVec[e2], Wfc[e2*80+tid], acc);
        out[((size_t)b*255 + t)*80 + tid] = acc + bfc[tid];
      }
    }
    gsync(bar,w,ep);
  }
}

extern "C" void kernel_launch(void* const* d_in, const int* in_sizes, int n_in,
                              void* d_out, int out_size, void* d_ws, size_t ws_size,
                              hipStream_t stream) {
  const float* tgt  = (const float*)d_in[0];
  const float* enc  = (const float*)d_in[1];
  const int*   lens = (const int*)  d_in[2];
  const float* Wih0 = (const float*)d_in[3];
  const float* Whh0 = (const float*)d_in[4];
  const float* b0   = (const float*)d_in[5];
  const float* Wih1 = (const float*)d_in[6];
  const float* Whh1 = (const float*)d_in[7];
  const float* b1   = (const float*)d_in[8];
  const float* Wih2 = (const float*)d_in[9];
  const float* Whh2 = (const float*)d_in[10];
  const float* b2   = (const float*)d_in[11];
  const float* Wq   = (const float*)d_in[12];
  const float* Wfc  = (const float*)d_in[13];
  const float* bfc  = (const float*)d_in[14];

  const size_t need = 8192ull + ((size_t)ENC_OFF + (size_t)ENC_CNT)*4ull;
  const int ebf = (ws_size >= need) ? 1 : 0;

  hipMemsetAsync(d_ws, 0, 8192, stream);   // barrier counters
  sd_kernel<<<NBLK, NTHR, 0, stream>>>(tgt, enc, lens,
                                       Wih0, Whh0, b0,
                                       Wih1, Whh1, b1,
                                       Wih2, Whh2, b2,
                                       Wq, Wfc, bfc,
                                       (float*)d_out, d_ws, ebf);
}